// Round 16
// baseline (133.814 us; speedup 1.0000x reference)
//
#include <hip/hip_runtime.h>
#include <hip/hip_bf16.h>

typedef __attribute__((ext_vector_type(4))) float f32x4;
typedef __attribute__((ext_vector_type(8))) short s16x8;
typedef unsigned long long u64;

#define NB_ 4
#define N_ 4096
#define FI_ 256
#define FO_ 128
#define NROWS 16384       // NB_ * N_
#define SPLIT 2
#define NSTEPS ((N_ / SPLIT) / 32)   // 64 steps of 32 cols

// pack two f32 -> one u32 of 2 bf16 (RNE), first arg in low half
__device__ __forceinline__ unsigned pkbf(float a, float b) {
    __hip_bfloat162 t = __float22bfloat162_rn(make_float2(a, b));
    unsigned r; __builtin_memcpy(&r, &t, 4); return r;
}

typedef __attribute__((address_space(1))) const void CGV;
typedef __attribute__((address_space(3))) void LDSV;
__device__ __forceinline__ void gload16(const void* g, void* l) {
    __builtin_amdgcn_global_load_lds((CGV*)g, (LDSV*)l, 16, 0, 0);
}

__device__ __forceinline__ unsigned encf(float x) {
    unsigned u = __float_as_uint(x);
    return (u & 0x80000000u) ? ~u : (u | 0x80000000u);
}
__device__ __forceinline__ float decf(unsigned v) {
    unsigned u = (v & 0x80000000u) ? (v ^ 0x80000000u) : ~v;
    return __uint_as_float(u);
}

// ---------------- K0: pack W into bf16 hi/lo; zero maxenc ---------------
__global__ __launch_bounds__(256) void k0_packw(
    const float* __restrict__ Ww, __hip_bfloat16* __restrict__ whi,
    __hip_bfloat16* __restrict__ wlo, unsigned* __restrict__ maxenc)
{
    int idx = blockIdx.x * 256 + threadIdx.x;           // 32768 elems
    if (blockIdx.x == 0 && threadIdx.x < NB_) maxenc[threadIdx.x] = 0u;
    float v = Ww[idx];
    __hip_bfloat16 hi = __float2bfloat16(v);
    whi[idx] = hi;
    wlo[idx] = __float2bfloat16(v - __bfloat162float(hi));
}

// ---------------- K1: Wh GEMM + fused epilogue (+ per-batch max) --------
// 1024 blocks x 16 rows(j). Emits WhTf = fragment-major bf16 tiles:
// WhTf[b][jblk][frag o>>4][lane (o&15)+16*(jin>>3)][elem jin&7]
__global__ __launch_bounds__(256) void k1_wh(
    const float* __restrict__ h, const __hip_bfloat16* __restrict__ whi,
    const __hip_bfloat16* __restrict__ wlo, const float* __restrict__ Wb,
    const float* __restrict__ aw, const float* __restrict__ ab,
    short* __restrict__ WhTf, float* __restrict__ srcv,
    unsigned* __restrict__ auxp, unsigned* __restrict__ maxenc)
{
    __shared__ float lds[16][132];
    __shared__ float dbsh[16];
    const int tid = threadIdx.x;
    const int w = tid >> 6, l = tid & 63;
    const int lr = l & 15, g = l >> 4;
    const int r0 = blockIdx.x * 16;
    const float* hp = h + (size_t)(r0 + lr) * FI_ + g * 8;

    f32x4 acc[2] = {(f32x4)0.f, (f32x4)0.f};

    #pragma unroll
    for (int kt = 0; kt < 8; ++kt) {
        f32x4 x0 = *(const f32x4*)(hp + kt * 32);
        f32x4 x1 = *(const f32x4*)(hp + kt * 32 + 4);
        float xx[8];
        #pragma unroll
        for (int t = 0; t < 4; ++t) { xx[t] = x0[t]; xx[t + 4] = x1[t]; }
        union { s16x8 v; unsigned u[4]; } ahi, alo;
        #pragma unroll
        for (int t = 0; t < 4; ++t) {
            float a0 = xx[2 * t], a1 = xx[2 * t + 1];
            unsigned uh = pkbf(a0, a1);
            ahi.u[t] = uh;
            float h0f = __uint_as_float(uh << 16);
            float h1f = __uint_as_float(uh & 0xffff0000u);
            alo.u[t] = pkbf(a0 - h0f, a1 - h1f);
        }
        #pragma unroll
        for (int c = 0; c < 2; ++c) {
            const int o = w * 32 + c * 16 + lr;
            s16x8 bh = *(const s16x8*)(whi + (size_t)o * FI_ + kt * 32 + g * 8);
            s16x8 bl = *(const s16x8*)(wlo + (size_t)o * FI_ + kt * 32 + g * 8);
            acc[c] = __builtin_amdgcn_mfma_f32_16x16x32_bf16(ahi.v, bh, acc[c], 0, 0, 0);
            acc[c] = __builtin_amdgcn_mfma_f32_16x16x32_bf16(alo.v, bh, acc[c], 0, 0, 0);
            acc[c] = __builtin_amdgcn_mfma_f32_16x16x32_bf16(ahi.v, bl, acc[c], 0, 0, 0);
        }
    }

    #pragma unroll
    for (int c = 0; c < 2; ++c) {
        int col = w * 32 + c * 16 + lr;
        float wb = Wb[col];
        #pragma unroll
        for (int kk = 0; kk < 4; ++kk)
            lds[g * 4 + kk][col] = acc[c][kk] + wb;   // local j x o
    }
    __syncthreads();

    {   // WhTf fragment-major store: thread -> (o = t>>1, joct = t&1), 16 B
        const int o = tid >> 1, joct = tid & 1;
        const int jblk = (r0 & 4095) >> 5;
        const int bb = r0 >> 12;
        const int lb = ((r0 >> 3) & 3) + joct;        // jin>>3
        union { s16x8 v; unsigned u[4]; } af;
        #pragma unroll
        for (int q = 0; q < 4; ++q)
            af.u[q] = pkbf(lds[joct * 8 + 2 * q][o], lds[joct * 8 + 2 * q + 1][o]);
        short* dst = WhTf + (((size_t)bb * 128 + jblk) * 8 + (o >> 4)) * 512
                          + ((o & 15) + 16 * lb) * 8;
        *(s16x8*)dst = af.v;
    }

    {   // per-row src/dst dots + exp tables + block max -> atomic
        const int row = tid >> 4, seg = tid & 15;
        float sp = 0.f, dp = 0.f;
        #pragma unroll
        for (int i = 0; i < 8; ++i) {
            float v = lds[row][seg * 8 + i];
            sp += v * aw[seg * 8 + i];
            dp += v * aw[FO_ + seg * 8 + i];
        }
        #pragma unroll
        for (int off = 8; off >= 1; off >>= 1) {
            sp += __shfl_xor(sp, off);
            dp += __shfl_xor(dp, off);
        }
        if (seg == 0) {
            int r = r0 + row;
            srcv[r] = sp;
            float db = dp + ab[0];
            dbsh[row] = db;
            auxp[r] = pkbf(__expf(db), __expf(0.01f * db));   // lo=e1, hi=e2
        }
        __syncthreads();
        if (tid == 0) {
            float m = dbsh[0];
            #pragma unroll
            for (int i = 1; i < 16; ++i) m = fmaxf(m, dbsh[i]);
            atomicMax(&maxenc[r0 >> 12], encf(m));
        }
    }
}

// ---------------- K3: champion staging structure, 32-row blocks ---------
// grid (512, SPLIT): x = b*128 + rowblk(32 rows). 4 waves:
//   wave w: rh=w&1 (16 rows), oh=w>>1 (o-half, 64 cols)
// Dual 2-ring LDS staging (adj swizzled, WhTf fragment-major contiguous),
// aux reg depth-1 prefetch, plain per-step __syncthreads (R9 structure).
__global__ __launch_bounds__(256, 4) void k3_gat(
    const int* __restrict__ adj, const short* __restrict__ WhTf,
    const float* __restrict__ srcv, const unsigned* __restrict__ auxp,
    const unsigned* __restrict__ maxenc, float* __restrict__ pacc,
    float* __restrict__ prow)
{
    __shared__ int adjb[2][32][32];            // 2 x 4 KB, 16B-chunk swizzled
    __shared__ __hip_bfloat16 whb[2][4096];    // 2 x 8 KB, fragment-major
    __shared__ float rsum[32];

    const int t = threadIdx.x;
    const int w = t >> 6, l = t & 63;
    const int lr = l & 15, g = l >> 4;
    const int rh = w & 1, oh = w >> 1;
    const int b = blockIdx.x >> 7;
    const int rblk = (blockIdx.x & 127) * 32;             // block row base
    const int bN = b * N_;
    const int j0 = blockIdx.y * (N_ / SPLIT);

    float C1, C2;
    {
        int r = rblk + rh * 16 + lr;
        float s = srcv[bN + r];
        float eub = s + decf(maxenc[b]);
        float m = fmaxf(eub, 0.01f * eub);                // >= row max of LR(e)
        C1 = __expf(s - m);
        C2 = __expf(0.01f * s - m);
    }

    const unsigned* axp = auxp + (size_t)bN + j0 + g * 8;
    const short* whsrc = WhTf + ((size_t)b * 128 + (j0 >> 5)) * 4096;

    f32x4 acc[4];
    #pragma unroll
    for (int ot = 0; ot < 4; ++ot) acc[ot] = (f32x4)0.f;
    float rs = 0.f;

    // adj stage: 256 slots of 16B, 1/thread; LDS chunk c holds src c^(r&7)
    auto stage_adj = [&](int bi, int s) {
        const int jb = j0 + s * 32;
        const int r = t >> 3, c = t & 7;
        gload16(adj + (size_t)(bN + rblk + r) * N_ + jb + ((c ^ (r & 7)) << 2),
                &adjb[bi][0][0] + (size_t)w * 256);
    };
    // WhTf stage: fully contiguous 8 KB
    auto stage_wh = [&](int bi, int s) {
        const short* src = whsrc + (size_t)s * 4096;
        #pragma unroll
        for (int i = 0; i < 2; ++i)
            gload16(src + (size_t)(i * 256 + t) * 8,
                    &whb[bi][0] + (size_t)(i * 256 + w * 64) * 8);
    };

    uint4 xc0, xc1;
    stage_adj(0, 0);
    stage_wh(0, 0);
    xc0 = *(const uint4*)(axp);
    xc1 = *(const uint4*)(axp + 4);
    __syncthreads();
    int cur = 0;

    for (int s = 0; s < NSTEPS; ++s) {
        uint4 xn0 = {0, 0, 0, 0}, xn1 = {0, 0, 0, 0};
        const bool more = (s + 1 < NSTEPS);
        if (more) {
            stage_adj(cur ^ 1, s + 1);
            stage_wh(cur ^ 1, s + 1);
            const int jn = (s + 1) * 32;
            xn0 = *(const uint4*)(axp + jn);
            xn1 = *(const uint4*)(axp + jn + 4);
        }

        // decode this wave's rowset
        const unsigned ax[8] = {xc0.x, xc0.y, xc0.z, xc0.w,
                                xc1.x, xc1.y, xc1.z, xc1.w};
        const int R = rh * 16 + lr;
        const int4 a0 = *(const int4*)&adjb[cur][R][((2 * g) ^ (R & 7)) << 2];
        const int4 a1 = *(const int4*)&adjb[cur][R][((2 * g + 1) ^ (R & 7)) << 2];
        const int av[8] = {a0.x, a0.y, a0.z, a0.w, a1.x, a1.y, a1.z, a1.w};
        s16x8 Bf[4];
        #pragma unroll
        for (int ot = 0; ot < 4; ++ot)
            Bf[ot] = *(const s16x8*)&whb[cur][(size_t)((oh * 4 + ot) * 64 + l) * 8];

        float p[8];
        #pragma unroll
        for (int e = 0; e < 8; ++e) {
            float e1f = __uint_as_float(ax[e] << 16);
            float e2f = __uint_as_float(ax[e] & 0xffff0000u);
            float v = fmaxf(e1f * C1, e2f * C2);          // exact LR softmax p
            p[e] = (av[e] > 0) ? v : 0.f;
            rs += p[e];
        }
        union { s16x8 v; unsigned u[4]; } af;
        af.u[0] = pkbf(p[0], p[1]); af.u[1] = pkbf(p[2], p[3]);
        af.u[2] = pkbf(p[4], p[5]); af.u[3] = pkbf(p[6], p[7]);

        #pragma unroll
        for (int ot = 0; ot < 4; ++ot)
            acc[ot] = __builtin_amdgcn_mfma_f32_16x16x32_bf16(
                af.v, Bf[ot], acc[ot], 0, 0, 0);

        __syncthreads();    // next-step DMA landed during compute
        xc0 = xn0; xc1 = xn1;
        cur ^= 1;
    }

    // row-sums: reduce over g-groups; park per block-row
    rs += __shfl_xor(rs, 16);
    rs += __shfl_xor(rs, 32);
    if (oh == 0 && g == 0) rsum[rh * 16 + lr] = rs;
    __syncthreads();

    const size_t sb = (size_t)blockIdx.y * ((size_t)NROWS * FO_);
    #pragma unroll
    for (int kk = 0; kk < 4; ++kk) {
        int rloc = rh * 16 + g * 4 + kk;
        int grow = bN + rblk + rloc;
        float* pp = pacc + sb + (size_t)grow * FO_ + oh * 64 + lr;
        #pragma unroll
        for (int ot = 0; ot < 4; ++ot)
            pp[ot * 16] = acc[ot][kk];
        if (oh == 0 && lr == 0)
            prow[blockIdx.y * NROWS + grow] = rsum[rloc];
    }
}

// ---------------- K4: combine split partials + normalize (float4) -------
__global__ __launch_bounds__(256) void k4_comb(
    const float* __restrict__ pacc, const float* __restrict__ prow,
    float* __restrict__ out)
{
    const int i4 = blockIdx.x * 256 + threadIdx.x;       // 524288 float4s
    const int grow = i4 >> 5;                            // 32 float4 per row
    f32x4 s = (f32x4)0.f;
    float rs = 0.f;
    #pragma unroll
    for (int si = 0; si < SPLIT; ++si) {
        s += *(const f32x4*)(pacc + (size_t)si * ((size_t)NROWS * FO_) + (size_t)i4 * 4);
        rs += prow[si * NROWS + grow];
    }
    float inv = 1.0f / rs;
    f32x4 o = s * inv;
    *(f32x4*)(out + (size_t)i4 * 4) = o;
}

extern "C" void kernel_launch(void* const* d_in, const int* in_sizes, int n_in,
                              void* d_out, int out_size, void* d_ws, size_t ws_size,
                              hipStream_t stream)
{
    const float* h  = (const float*)d_in[0];
    const int* adj  = (const int*)d_in[1];
    const float* Ww = (const float*)d_in[2];
    const float* Wb = (const float*)d_in[3];
    const float* aw = (const float*)d_in[4];
    const float* ab = (const float*)d_in[5];
    float* out = (float*)d_out;

    char* wsb = (char*)d_ws;                             // ws_size ~1 GB
    float* pacc          = (float*)wsb;                               // 16 MB
    short* WhTf          = (short*)(wsb + 33554432u);                 // 4 MB
    char* aux            = wsb + 37748736u;
    float* srcv          = (float*)(aux);                             // 64 KB
    unsigned* auxp       = (unsigned*)(aux + (64u << 10));            // 64 KB
    __hip_bfloat16* whi  = (__hip_bfloat16*)(aux + (128u << 10));     // 64 KB
    __hip_bfloat16* wlo  = (__hip_bfloat16*)(aux + (192u << 10));     // 64 KB
    unsigned* maxenc     = (unsigned*)(aux + (256u << 10));           // 16 B
    float* prow          = (float*)(aux + (320u << 10));              // 128 KB

    k0_packw<<<128, 256, 0, stream>>>(Ww, whi, wlo, maxenc);
    k1_wh<<<1024, 256, 0, stream>>>(h, whi, wlo, Wb, aw, ab, WhTf, srcv, auxp, maxenc);
    dim3 g3(NB_ * 128, SPLIT);
    k3_gat<<<g3, 256, 0, stream>>>(adj, WhTf, srcv, auxp, maxenc, pacc, prow);
    k4_comb<<<2048, 256, 0, stream>>>(pacc, prow, out);
}